// Round 5
// baseline (79.112 us; speedup 1.0000x reference)
//
#include <hip/hip_runtime.h>

// Mutual information, N=8 images 384x384, 50 soft bins.
// R16 = R15 with the memset dispatch ELIMINATED: hgram blocks write their
// 32x32 G-partials to private slots hgp[n][slice][1024] (plain coalesced
// stores, no atomics, buffer fully overwritten -> no zeroing), and finalize
// sums the 96 slice partials per image. Batch-global T = corner telescopes
// summed over all 8 images x 96 slices (32 pairs x width-32 shuffle reduce).
// Two dispatches total.
//
// K1 hgram: 28 even sigmoid edges per element (t_j = sigmoid(10v-0.2j), x256),
//   G = te_x . te_y^T via 32x32x16 MFMA (each wave owns a 64-wide k-quarter,
//   full 32x32 partial in 16 regs; X/Y slabs each written once + read once),
//   4-wave LDS reduce, 4 coalesced dword stores/thread to hgp.
// K2 finalize (8 blocks x 1024): G_n = sum_s hgp[n][s]; hgram = W G W^T,
//   W = D*M (cubic-interp odd edges, 4-banded {1,7,-9,1}/16 even,
//   {-1,9,-7,-1}/16 odd); marginals telescope (sum_b W[b] = e_1 - e_26);
//   MI log-sum; atomicAdd to out (zeroed by a store in hgram, kernel-boundary
//   ordered).

#define D_TOTAL   147456
#define NBATCH    8
#define BINS      50
#define NEDGE     28                       // even edges j=-2..52
#define KSLICES   96                       // 768 blocks = 3/CU, single generation
#define KC        256                      // d-columns per block iteration
#define SLICE_LEN (D_TOTAL / KSLICES)      // 1536
#define ITERS     (SLICE_LEN / KC)         // 6
#define LDS_STR   280                      // 140 dwords = 12 mod 32: conflict-free b128 frags

typedef _Float16 half8  __attribute__((ext_vector_type(8)));
typedef __fp16   fp16x2 __attribute__((ext_vector_type(2)));   // cvt_pkrtz return type
typedef float    f32x16 __attribute__((ext_vector_type(16)));

struct Tab { float c[NEDGE]; };
constexpr Tab make_tab() {
    Tab t{};
    double c = 0.6703200460356393;          // e^{-0.4} (edge j=-2)
    const double lam = 1.4918246976412703;  // e^{0.4} between even edges
    for (int i = 0; i < NEDGE; ++i) { t.c[i] = (float)c; c *= lam; }
    return t;
}
constexpr Tab TAB = make_tab();

__global__ __launch_bounds__(256, 3) void hgram_kernel(const float* __restrict__ im1,
                                                       const float* __restrict__ im2,
                                                       float* __restrict__ hgp,
                                                       float* __restrict__ out) {
    __shared__ __align__(16) _Float16 Xs[32][LDS_STR];
    __shared__ __align__(16) _Float16 Ys[32][LDS_STR];

    const int tid   = threadIdx.x;
    const int slice = blockIdx.x;
    const int n     = blockIdx.y;
    const int base  = n * D_TOTAL + slice * SLICE_LEN;

    if (slice == 0 && n == 0 && tid == 0) out[0] = 0.f;   // ordered by kernel boundary

    {   // zero pad rows 28..31 once (staging only rewrites rows 0..27)
        unsigned* px = (unsigned*)&Xs[28][0];
        unsigned* py = (unsigned*)&Ys[28][0];
        for (int i = tid; i < 4 * LDS_STR / 2; i += 256) { px[i] = 0u; py[i] = 0u; }
    }

    // staging: threads 0..127 stage X element-pair (2h, 2h+1); 128..255 stage Y
    const int h    = tid & 127;
    const int isY  = tid >> 7;
    const float2* src2 = (const float2*)((isY ? im2 : im1) + base);
    _Float16* plane = isY ? &Ys[0][0] : &Xs[0][0];
    _Float16* dst   = plane + 2 * h;            // pair base within row

    const int lane  = tid & 63;
    const int w     = tid >> 6;
    const int kw    = w << 6;                   // wave's 64-wide k-quarter
    const int row32 = lane & 31;                // A row / B col (edge index)
    const int kg    = (lane >> 5) << 3;         // k sub-offset: 0 or 8

    f32x16 acc = {0.f,0.f,0.f,0.f,0.f,0.f,0.f,0.f,
                  0.f,0.f,0.f,0.f,0.f,0.f,0.f,0.f};

    float2 v = src2[h];
    for (int it = 0; it < ITERS; ++it) {
        float2 nv = {0.f, 0.f};
        if (it + 1 < ITERS) nv = src2[(it + 1) * (KC / 2) + h];   // prefetch
        // ---- stage 2 elements: 28 even-edge sigmoids each (x256, f16, packed) ----
        {
            const float Ea = __builtin_amdgcn_exp2f(v.x * -14.426950408889634f); // e^{-10va}
            const float Eb = __builtin_amdgcn_exp2f(v.y * -14.426950408889634f); // e^{-10vb}
            #pragma unroll
            for (int i = 0; i < NEDGE; ++i) {
                const float c = TAB.c[i];       // compile-time literal
                float ta = __builtin_amdgcn_rcpf(__builtin_fmaf(c * Ea, 0.00390625f, 0.00390625f));
                float tb = __builtin_amdgcn_rcpf(__builtin_fmaf(c * Eb, 0.00390625f, 0.00390625f));
                fp16x2 p = __builtin_amdgcn_cvt_pkrtz(ta, tb);    // 256/(1+u) pair
                *(fp16x2*)(dst + i * LDS_STR) = p;                // one ds_write_b32
            }
        }
        __syncthreads();
        // ---- 32x32x16 MFMA over this wave's k-quarter: 8 ds_read_b128 total ----
        #pragma unroll
        for (int s = 0; s < 4; ++s) {
            const int k0 = kw + s * 16 + kg;
            half8 a = *(const half8*)&Xs[row32][k0];
            half8 b = *(const half8*)&Ys[row32][k0];
            acc = __builtin_amdgcn_mfma_f32_32x32x16_f16(a, b, acc, 0, 0, 0);
        }
        __syncthreads();
        v = nv;
    }

    // ---- reduce 4 per-wave partials via LDS (Xs reused; last barrier passed) ----
    float* const Pf = (float*)&Xs[0][0];        // 4*32*32 f32 = 16 KB <= 17.9 KB
    {
        float* Pw = Pf + (w << 10);
        const int prow_base = (lane >> 5) << 2; // 0 or 4
        #pragma unroll
        for (int reg = 0; reg < 16; ++reg) {
            const int prow = (reg & 3) + ((reg >> 2) << 3) + prow_base;
            Pw[prow * 32 + row32] = acc[reg];   // C/D: col=lane&31, verified map
        }
    }
    __syncthreads();

    // epilogue: sum partials, plain coalesced stores to this block's hgp slot
    float* hp = hgp + (n * KSLICES + slice) * 1024;
    #pragma unroll
    for (int k = 0; k < 4; ++k) {
        const int e = tid + k * 256;            // stride-256: conflict-free LDS reads
        hp[e] = Pf[e] + Pf[1024 + e] + Pf[2048 + e] + Pf[3072 + e];
    }
}

__global__ __launch_bounds__(1024) void finalize_kernel(const float* __restrict__ hgp,
                                                        float* __restrict__ out) {
    __shared__ float Gs[NEDGE][29];           // own-n G, stride 29 vs bank conflicts
    __shared__ float mx[BINS], my[BINS];
    __shared__ float ct[32];                  // (image,corner) slice-sums
    __shared__ float red[16];
    __shared__ float sT;
    const int tid = threadIdx.x;
    const int n   = blockIdx.x;

    // own-image G: element tid = (r,c); sum 96 slice partials (coalesced)
    {
        const int r = tid >> 5, c = tid & 31;
        if (r < NEDGE && c < NEDGE) {
            const float* p = hgp + n * (KSLICES * 1024) + tid;
            float s = 0.f;
            #pragma unroll 8
            for (int sl = 0; sl < KSLICES; ++sl) s += p[sl * 1024];
            Gs[r][c] = s;
        }
    }
    // batch-global T: 32 (image,corner) pairs x 96 slices, width-32 reduce.
    // corners: cn=0:(1,1)+  cn=1:(1,26)-  cn=2:(26,1)-  cn=3:(26,26)+
    {
        const int pr = tid >> 5;              // pair index 0..31
        const int j  = tid & 31;
        const int b  = pr >> 2;
        const int cn = pr & 3;
        const int cidx = (cn < 2 ? 32 : 832) + ((cn & 1) ? 26 : 1);
        const float* p = hgp + b * (KSLICES * 1024) + cidx;
        float vv = p[j * 1024] + p[(j + 32) * 1024] + p[(j + 64) * 1024];
        #pragma unroll
        for (int o = 16; o > 0; o >>= 1) vv += __shfl_down(vv, o, 32);
        if (j == 0) ct[pr] = vv;
    }
    __syncthreads();
    if (tid == 0) {
        float t = 0.f;
        #pragma unroll
        for (int pr = 0; pr < 32; ++pr) {
            const int cn = pr & 3;
            t += ((cn == 0 || cn == 3) ? 1.f : -1.f) * ct[pr];
        }
        sT = t;
    }
    __syncthreads();

    // marginals: 100 tasks, 4-MAC band-dot (W row applied to G*(e1-e26))
    if (tid < 2 * BINS) {
        const int which = (tid >= BINS) ? 1 : 0;
        const int b = which ? tid - BINS : tid;
        const int q = b >> 1;
        float w0, w1, w2, w3;
        if (b & 1) { w0 = -1.f; w1 = 9.f; w2 = -7.f; w3 = -1.f; }
        else       { w0 =  1.f; w1 = 7.f; w2 = -9.f; w3 =  1.f; }
        float m;
        if (which == 0) {
            m = w0 * (Gs[q][1]   - Gs[q][26])
              + w1 * (Gs[q+1][1] - Gs[q+1][26])
              + w2 * (Gs[q+2][1] - Gs[q+2][26])
              + w3 * (Gs[q+3][1] - Gs[q+3][26]);
            mx[b] = m * 0.0625f;
        } else {
            m = w0 * (Gs[1][q]   - Gs[26][q])
              + w1 * (Gs[1][q+1] - Gs[26][q+1])
              + w2 * (Gs[1][q+2] - Gs[26][q+2])
              + w3 * (Gs[1][q+3] - Gs[26][q+3]);
            my[b] = m * 0.0625f;
        }
    }
    __syncthreads();

    // MI pass: 2x2 entry blocks share one 4x4 G block (task = b-pair, c-pair)
    const float invT = 1.0f / sT;
    const float invT2 = invT * invT;
    float mi = 0.f;
    for (int task = tid; task < 25 * 25; task += 1024) {
        const int bp = task / 25, cp = task - bp * 25;
        float g[4][4];
        #pragma unroll
        for (int r = 0; r < 4; ++r)
            #pragma unroll
            for (int s = 0; s < 4; ++s) g[r][s] = Gs[bp + r][cp + s];
        float rde[4], rdo[4];
        #pragma unroll
        for (int r = 0; r < 4; ++r) {
            rde[r] =  g[r][0] + 7.f * g[r][1] - 9.f * g[r][2] + g[r][3];
            rdo[r] = -g[r][0] + 9.f * g[r][1] - 7.f * g[r][2] - g[r][3];
        }
        const float hee = ( rde[0] + 7.f*rde[1] - 9.f*rde[2] + rde[3]) * (1.f/256.f);
        const float heo = ( rdo[0] + 7.f*rdo[1] - 9.f*rdo[2] + rdo[3]) * (1.f/256.f);
        const float hoe = (-rde[0] + 9.f*rde[1] - 7.f*rde[2] - rde[3]) * (1.f/256.f);
        const float hoo = (-rdo[0] + 9.f*rdo[1] - 7.f*rdo[2] - rdo[3]) * (1.f/256.f);
        const int b0 = 2 * bp, c0 = 2 * cp;
        {
            float p = hee * invT, jo = mx[b0] * my[c0] * invT2;
            mi += p * (__logf(p + 1e-8f) - __logf(jo + 1e-8f));
        }
        {
            float p = heo * invT, jo = mx[b0] * my[c0 + 1] * invT2;
            mi += p * (__logf(p + 1e-8f) - __logf(jo + 1e-8f));
        }
        {
            float p = hoe * invT, jo = mx[b0 + 1] * my[c0] * invT2;
            mi += p * (__logf(p + 1e-8f) - __logf(jo + 1e-8f));
        }
        {
            float p = hoo * invT, jo = mx[b0 + 1] * my[c0 + 1] * invT2;
            mi += p * (__logf(p + 1e-8f) - __logf(jo + 1e-8f));
        }
    }
    #pragma unroll
    for (int o = 32; o > 0; o >>= 1) mi += __shfl_down(mi, o, 64);
    if ((tid & 63) == 0) red[tid >> 6] = mi;
    __syncthreads();
    if (tid == 0) {
        float t = 0.f;
        #pragma unroll
        for (int i = 0; i < 16; ++i) t += red[i];
        atomicAdd(&out[0], t);
    }
}

extern "C" void kernel_launch(void* const* d_in, const int* in_sizes, int n_in,
                              void* d_out, int out_size, void* d_ws, size_t ws_size,
                              hipStream_t stream) {
    const float* im1 = (const float*)d_in[0];
    const float* im2 = (const float*)d_in[1];
    float* out = (float*)d_out;
    float* hgp = (float*)d_ws;   // [8][96][1024] f32 = 3 MB, fully overwritten

    hgram_kernel<<<dim3(KSLICES, NBATCH), dim3(256), 0, stream>>>(im1, im2, hgp, out);
    finalize_kernel<<<dim3(NBATCH), dim3(1024), 0, stream>>>(hgp, out);
}

// Round 6
// 75.263 us; speedup vs baseline: 1.0511x; 1.0511x over previous
//
#include <hip/hip_runtime.h>

// Mutual information, N=8 images 384x384, 50 soft bins.
// R17 = revert to R15 (verified 75.2us). R16's memset-free partial-buffer
// variant regressed (finalize read 3 MB latency-bound on 8 CUs: +4.5us >
// memset's 1us). R15 budget: ~66us fixed harness overhead + memset ~1 +
// hgram ~6.3 (LDS-pipe-bound at its structural floor: X/Y slabs each
// written once + read once) + finalize ~1.5 + gaps ~0.5.
//
// K1 hgram: 28 even sigmoid edges per element (t_j = sigmoid(10v-0.2j), x256),
//   G = te_x . te_y^T via 32x32x16 MFMA (each wave owns a 64-wide k-quarter,
//   full 32x32 partial in 16 regs), 4-wave LDS reduce, 28x28 atomic epilogue
//   into memset-zeroed hg[8][32][32].
// K2 finalize (8 blocks, one per image): hgram = W G W^T, W = D*M (cubic-
//   interp odd edges, 4-banded {1,7,-9,1}/16 even, {-1,9,-7,-1}/16 odd);
//   marginals telescope (sum_b W[b] = e_1 - e_26); batch-global T from the
//   4 corner telescopes per image; MI log-sum; atomicAdd into out (zeroed by
//   a store in hgram block (0,0), ordered by the kernel boundary).

#define D_TOTAL   147456
#define NBATCH    8
#define BINS      50
#define NEDGE     28                       // even edges j=-2..52
#define KSLICES   96                       // 768 blocks = 3/CU, single generation
#define KC        256                      // d-columns per block iteration
#define SLICE_LEN (D_TOTAL / KSLICES)      // 1536
#define ITERS     (SLICE_LEN / KC)         // 6
#define LDS_STR   280                      // 140 dwords = 12 mod 32: conflict-free b128 frags

typedef _Float16 half8  __attribute__((ext_vector_type(8)));
typedef __fp16   fp16x2 __attribute__((ext_vector_type(2)));   // cvt_pkrtz return type
typedef float    f32x16 __attribute__((ext_vector_type(16)));

struct Tab { float c[NEDGE]; };
constexpr Tab make_tab() {
    Tab t{};
    double c = 0.6703200460356393;          // e^{-0.4} (edge j=-2)
    const double lam = 1.4918246976412703;  // e^{0.4} between even edges
    for (int i = 0; i < NEDGE; ++i) { t.c[i] = (float)c; c *= lam; }
    return t;
}
constexpr Tab TAB = make_tab();

__global__ __launch_bounds__(256, 3) void hgram_kernel(const float* __restrict__ im1,
                                                       const float* __restrict__ im2,
                                                       float* __restrict__ hg,
                                                       float* __restrict__ out) {
    __shared__ __align__(16) _Float16 Xs[32][LDS_STR];
    __shared__ __align__(16) _Float16 Ys[32][LDS_STR];

    const int tid   = threadIdx.x;
    const int slice = blockIdx.x;
    const int n     = blockIdx.y;
    const int base  = n * D_TOTAL + slice * SLICE_LEN;

    if (slice == 0 && n == 0 && tid == 0) out[0] = 0.f;   // ordered by kernel boundary

    {   // zero pad rows 28..31 once (staging only rewrites rows 0..27)
        unsigned* px = (unsigned*)&Xs[28][0];
        unsigned* py = (unsigned*)&Ys[28][0];
        for (int i = tid; i < 4 * LDS_STR / 2; i += 256) { px[i] = 0u; py[i] = 0u; }
    }

    // staging: threads 0..127 stage X element-pair (2h, 2h+1); 128..255 stage Y
    const int h    = tid & 127;
    const int isY  = tid >> 7;
    const float2* src2 = (const float2*)((isY ? im2 : im1) + base);
    _Float16* plane = isY ? &Ys[0][0] : &Xs[0][0];
    _Float16* dst   = plane + 2 * h;            // pair base within row

    const int lane  = tid & 63;
    const int w     = tid >> 6;
    const int kw    = w << 6;                   // wave's 64-wide k-quarter
    const int row32 = lane & 31;                // A row / B col (edge index)
    const int kg    = (lane >> 5) << 3;         // k sub-offset: 0 or 8

    f32x16 acc = {0.f,0.f,0.f,0.f,0.f,0.f,0.f,0.f,
                  0.f,0.f,0.f,0.f,0.f,0.f,0.f,0.f};

    float2 v = src2[h];
    for (int it = 0; it < ITERS; ++it) {
        float2 nv = {0.f, 0.f};
        if (it + 1 < ITERS) nv = src2[(it + 1) * (KC / 2) + h];   // prefetch
        // ---- stage 2 elements: 28 even-edge sigmoids each (x256, f16, packed) ----
        {
            const float Ea = __builtin_amdgcn_exp2f(v.x * -14.426950408889634f); // e^{-10va}
            const float Eb = __builtin_amdgcn_exp2f(v.y * -14.426950408889634f); // e^{-10vb}
            #pragma unroll
            for (int i = 0; i < NEDGE; ++i) {
                const float c = TAB.c[i];       // compile-time literal
                float ta = __builtin_amdgcn_rcpf(__builtin_fmaf(c * Ea, 0.00390625f, 0.00390625f));
                float tb = __builtin_amdgcn_rcpf(__builtin_fmaf(c * Eb, 0.00390625f, 0.00390625f));
                fp16x2 p = __builtin_amdgcn_cvt_pkrtz(ta, tb);    // 256/(1+u) pair
                *(fp16x2*)(dst + i * LDS_STR) = p;                // one ds_write_b32
            }
        }
        __syncthreads();
        // ---- 32x32x16 MFMA over this wave's k-quarter: 8 ds_read_b128 total ----
        #pragma unroll
        for (int s = 0; s < 4; ++s) {
            const int k0 = kw + s * 16 + kg;
            half8 a = *(const half8*)&Xs[row32][k0];
            half8 b = *(const half8*)&Ys[row32][k0];
            acc = __builtin_amdgcn_mfma_f32_32x32x16_f16(a, b, acc, 0, 0, 0);
        }
        __syncthreads();
        v = nv;
    }

    // ---- reduce 4 per-wave partials via LDS (Xs reused; last barrier passed) ----
    float* const Pf = (float*)&Xs[0][0];        // 4*32*32 f32 = 16 KB <= 17.9 KB
    {
        float* Pw = Pf + (w << 10);
        const int prow_base = (lane >> 5) << 2; // 0 or 4
        #pragma unroll
        for (int reg = 0; reg < 16; ++reg) {
            const int prow = (reg & 3) + ((reg >> 2) << 3) + prow_base;
            Pw[prow * 32 + row32] = acc[reg];   // C/D: col=lane&31, verified map
        }
    }
    __syncthreads();

    // epilogue: sum partials, atomic-add the 28x28 region of G
    float* hgn = hg + n * 1024;
    for (int e = tid; e < 1024; e += 256) {
        const int r = e >> 5, c = e & 31;
        if (r < NEDGE && c < NEDGE) {
            float s = Pf[e] + Pf[1024 + e] + Pf[2048 + e] + Pf[3072 + e];
            atomicAdd(&hgn[e], s);
        }
    }
}

__global__ __launch_bounds__(1024) void finalize_kernel(const float* __restrict__ hg,
                                                        float* __restrict__ out) {
    __shared__ float Gs[NEDGE][29];           // own-n G, stride 29 vs bank conflicts
    __shared__ float mx[BINS], my[BINS];
    __shared__ float red[16];
    __shared__ float sT;
    const int tid = threadIdx.x;
    const int n   = blockIdx.x;
    const float* hgn = hg + n * 1024;

    for (int idx = tid; idx < NEDGE * NEDGE; idx += 1024) {
        int r = idx / NEDGE, c = idx - r * NEDGE;
        Gs[r][c] = hgn[r * 32 + c];
    }
    if (tid == 0) {   // batch-global T: telescoped corners of all 8 images
        float t = 0.f;
        #pragma unroll
        for (int b = 0; b < NBATCH; ++b) {
            const float* p = hg + b * 1024;
            t += p[1 * 32 + 1] - p[1 * 32 + 26] - p[26 * 32 + 1] + p[26 * 32 + 26];
        }
        sT = t;
    }
    __syncthreads();

    // marginals: 100 tasks, 4-MAC band-dot (W row applied to G*(e1-e26))
    if (tid < 2 * BINS) {
        const int which = (tid >= BINS) ? 1 : 0;
        const int b = which ? tid - BINS : tid;
        const int q = b >> 1;
        float w0, w1, w2, w3;
        if (b & 1) { w0 = -1.f; w1 = 9.f; w2 = -7.f; w3 = -1.f; }
        else       { w0 =  1.f; w1 = 7.f; w2 = -9.f; w3 =  1.f; }
        float m;
        if (which == 0) {
            m = w0 * (Gs[q][1]   - Gs[q][26])
              + w1 * (Gs[q+1][1] - Gs[q+1][26])
              + w2 * (Gs[q+2][1] - Gs[q+2][26])
              + w3 * (Gs[q+3][1] - Gs[q+3][26]);
            mx[b] = m * 0.0625f;
        } else {
            m = w0 * (Gs[1][q]   - Gs[26][q])
              + w1 * (Gs[1][q+1] - Gs[26][q+1])
              + w2 * (Gs[1][q+2] - Gs[26][q+2])
              + w3 * (Gs[1][q+3] - Gs[26][q+3]);
            my[b] = m * 0.0625f;
        }
    }
    __syncthreads();

    // MI pass: 2x2 entry blocks share one 4x4 G block (task = b-pair, c-pair)
    const float invT = 1.0f / sT;
    const float invT2 = invT * invT;
    float mi = 0.f;
    for (int task = tid; task < 25 * 25; task += 1024) {
        const int bp = task / 25, cp = task - bp * 25;
        float g[4][4];
        #pragma unroll
        for (int r = 0; r < 4; ++r)
            #pragma unroll
            for (int s = 0; s < 4; ++s) g[r][s] = Gs[bp + r][cp + s];
        float rde[4], rdo[4];
        #pragma unroll
        for (int r = 0; r < 4; ++r) {
            rde[r] =  g[r][0] + 7.f * g[r][1] - 9.f * g[r][2] + g[r][3];
            rdo[r] = -g[r][0] + 9.f * g[r][1] - 7.f * g[r][2] - g[r][3];
        }
        const float hee = ( rde[0] + 7.f*rde[1] - 9.f*rde[2] + rde[3]) * (1.f/256.f);
        const float heo = ( rdo[0] + 7.f*rdo[1] - 9.f*rdo[2] + rdo[3]) * (1.f/256.f);
        const float hoe = (-rde[0] + 9.f*rde[1] - 7.f*rde[2] - rde[3]) * (1.f/256.f);
        const float hoo = (-rdo[0] + 9.f*rdo[1] - 7.f*rdo[2] - rdo[3]) * (1.f/256.f);
        const int b0 = 2 * bp, c0 = 2 * cp;
        {
            float p = hee * invT, jo = mx[b0] * my[c0] * invT2;
            mi += p * (__logf(p + 1e-8f) - __logf(jo + 1e-8f));
        }
        {
            float p = heo * invT, jo = mx[b0] * my[c0 + 1] * invT2;
            mi += p * (__logf(p + 1e-8f) - __logf(jo + 1e-8f));
        }
        {
            float p = hoe * invT, jo = mx[b0 + 1] * my[c0] * invT2;
            mi += p * (__logf(p + 1e-8f) - __logf(jo + 1e-8f));
        }
        {
            float p = hoo * invT, jo = mx[b0 + 1] * my[c0 + 1] * invT2;
            mi += p * (__logf(p + 1e-8f) - __logf(jo + 1e-8f));
        }
    }
    #pragma unroll
    for (int o = 32; o > 0; o >>= 1) mi += __shfl_down(mi, o, 64);
    if ((tid & 63) == 0) red[tid >> 6] = mi;
    __syncthreads();
    if (tid == 0) {
        float t = 0.f;
        #pragma unroll
        for (int i = 0; i < 16; ++i) t += red[i];
        atomicAdd(&out[0], t);
    }
}

extern "C" void kernel_launch(void* const* d_in, const int* in_sizes, int n_in,
                              void* d_out, int out_size, void* d_ws, size_t ws_size,
                              hipStream_t stream) {
    const float* im1 = (const float*)d_in[0];
    const float* im2 = (const float*)d_in[1];
    float* out = (float*)d_out;
    float* hg  = (float*)d_ws;   // [8][32][32] f32 = 32 KB

    (void)hipMemsetAsync(d_ws, 0, NBATCH * 1024 * sizeof(float), stream);
    hgram_kernel<<<dim3(KSLICES, NBATCH), dim3(256), 0, stream>>>(im1, im2, hg, out);
    finalize_kernel<<<dim3(NBATCH), dim3(1024), 0, stream>>>(hg, out);
}